// Round 10
// baseline (108.306 us; speedup 1.0000x reference)
//
#include <hip/hip_runtime.h>

#define TPB    256
#define NF     32
#define T_TOT  406
#define LLEN   2048
#define NPAIR  496
#define NCH    29          // chunks per batch; 29*14 = 406 exactly
#define WPB    14          // windows per chunk (7 window-pairs)
#define FSW    36          // fs row stride (words): bank-rotating, b128-friendly
#define ROWS   88          // staged rows: off(<=2) + 6*10 + 25 = 87 max
#define STSTR  15          // st row stride (float2), odd -> conflict-light
#define OTS    8           // ot row stride (u32 slots, 7 used, swizzled)

__device__ __forceinline__ unsigned int f2bf(float f) {
    unsigned int u = __float_as_uint(f);
    u += 0x7fffu + ((u >> 16) & 1u);           // RNE
    return u >> 16;
}

__global__ __launch_bounds__(TPB)
void tscorr_kernel(const float* __restrict__ x, float* __restrict__ out) {
    __shared__ float        fs[ROWS * FSW];    // 12672 B, [l][f]
    __shared__ float2       st[NF * STSTR];    //  3840 B, (sqrt20*mu, n) per (f,t)
    __shared__ unsigned int ot[NPAIR * OTS];   // 15872 B, 2xbf16-packed out tile

    const int tid = threadIdx.x;

    // XCD-pinned decode: all 29 chunks of batch b run on XCD b%8
    const int n     = blockIdx.x;
    const int xcd   = n & 7;
    const int slot  = n >> 3;            // 0..927
    const int bidx  = slot / NCH;        // 0..31
    const int chunk = slot - bidx * NCH; // 0..28
    const int b     = xcd + 8 * bidx;

    const int l0     = chunk * (WPB * 5);    // chunk*70
    const int lstart = l0 & ~3;              // 16B-aligned
    const int off    = l0 - lstart;          // 0 or 2
    const float* xb  = x + (size_t)b * NF * LLEN;

    // ---------------- stage: coalesced float4 loads -> fs[l][f] ----------------
    {
        const int f  = tid >> 3;             // 0..31
        const int p4 = tid & 7;              // 0..7
        #pragma unroll
        for (int it = 0; it < 3; ++it) {
            const int grp = p4 + it * 8;     // 0..23
            if (grp < 22) {                  // 22*4 = 88 rows
                const int pos = grp * 4;
                // lstart+pos+3 <= 1960+87 = 2047: always in bounds
                const float4 v = *(const float4*)&xb[f * LLEN + lstart + pos];
                fs[(pos + 0) * FSW + f] = v.x;
                fs[(pos + 1) * FSW + f] = v.y;
                fs[(pos + 2) * FSW + f] = v.z;
                fs[(pos + 3) * FSW + f] = v.w;
            }
        }
    }
    __syncthreads();

    // -------- main: thread = (pair-block pb, window-pair wp), 2 windows/thread -----
    // stats folded in: diagonal pair-blocks accumulate row sums via mask-FMA
    const bool active = (tid < 252);
    const int  wp = tid / 36;                // 0..6
    const int  pb = tid - wp * 36;           // 0..35
    int bi = 0, r2 = active ? pb : 0;
    while (r2 >= 8 - bi) { r2 -= 8 - bi; ++bi; }
    const int bj = bi + r2;
    const bool diag = active && (bi == bj);
    const float dm  = diag ? 1.0f : 0.0f;    // branchless stats mask

    float A0[4][4], A1[4][4];
    float Si0[4], Si1[4];
    if (active) {
        #pragma unroll
        for (int r = 0; r < 4; ++r) {
            Si0[r] = 0.f; Si1[r] = 0.f;
            #pragma unroll
            for (int c = 0; c < 4; ++c) { A0[r][c] = 0.f; A1[r][c] = 0.f; }
        }

        const float* pi = &fs[(off + wp * 10) * FSW + bi * 4];
        const float* pj = &fs[(off + wp * 10) * FSW + bj * 4];
        #pragma unroll
        for (int k = 0; k < 25; ++k) {       // windows share 15 of 25 rows
            const float4 vi = *(const float4*)&pi[k * FSW];   // base + imm offset
            const float4 vj = *(const float4*)&pj[k * FSW];
            const float xi[4] = {vi.x, vi.y, vi.z, vi.w};
            const float xj[4] = {vj.x, vj.y, vj.z, vj.w};
            if (k < 20) {
                #pragma unroll
                for (int r = 0; r < 4; ++r) {
                    #pragma unroll
                    for (int c = 0; c < 4; ++c)
                        A0[r][c] = fmaf(xi[r], xj[c], A0[r][c]);
                    Si0[r] = fmaf(dm, xi[r], Si0[r]);
                }
            }
            if (k >= 5) {
                #pragma unroll
                for (int r = 0; r < 4; ++r) {
                    #pragma unroll
                    for (int c = 0; c < 4; ++c)
                        A1[r][c] = fmaf(xi[r], xj[c], A1[r][c]);
                    Si1[r] = fmaf(dm, xi[r], Si1[r]);
                }
            }
        }

        // diagonal blocks publish stats: A[r][r] = sum x^2 (free), Si = sum x
        if (diag) {
            const int t0 = 2 * wp;
            #pragma unroll
            for (int r = 0; r < 4; ++r) {
                const float p0 = Si0[r] * 0.2236067977f;   // sqrt(20)*mu
                const float n0 = sqrtf(fmaxf(A0[r][r] - p0 * p0, 0.f));
                const float p1 = Si1[r] * 0.2236067977f;
                const float n1 = sqrtf(fmaxf(A1[r][r] - p1 * p1, 0.f));
                st[(bi * 4 + r) * STSTR + t0]     = make_float2(p0, n0);
                st[(bi * 4 + r) * STSTR + t0 + 1] = make_float2(p1, n1);
            }
        }
    }
    __syncthreads();                          // st visible

    // ---------------- epilogue: normalize both windows, pack 2xbf16 ----------------
    if (active) {
        const int t0 = 2 * wp;                // local even window
        float2 sj0[4], sj1[4];
        #pragma unroll
        for (int c = 0; c < 4; ++c) {
            sj0[c] = st[(bj * 4 + c) * STSTR + t0];
            sj1[c] = st[(bj * 4 + c) * STSTR + t0 + 1];
        }
        #pragma unroll
        for (int r = 0; r < 4; ++r) {
            const int fi = bi * 4 + r;
            const float2 si0 = st[fi * STSTR + t0];
            const float2 si1 = st[fi * STSTR + t0 + 1];
            #pragma unroll
            for (int c = 0; c < 4; ++c) {
                const int fj = bj * 4 + c;
                if (fj > fi) {
                    const int p = fi * (63 - fi) / 2 + (fj - fi - 1);
                    const float num0 = A0[r][c] - si0.x * sj0[c].x;
                    const float den0 = si0.y * sj0[c].y + 1e-8f;
                    const float num1 = A1[r][c] - si1.x * sj1[c].x;
                    const float den1 = si1.y * sj1[c].y + 1e-8f;
                    const float v0 = num0 * __builtin_amdgcn_rcpf(den0);
                    const float v1 = num1 * __builtin_amdgcn_rcpf(den1);
                    ot[p * OTS + ((wp + p) & 7)] = f2bf(v0) | (f2bf(v1) << 16);
                }
            }
        }
    }
    __syncthreads();

    // ------------- sweep: ot -> out[b][p][chunk*14 + 2wp + {0,1}], float2 ----------
    float* ob = out + (size_t)b * NPAIR * T_TOT + chunk * WPB;
    for (int k = tid; k < NPAIR * OTS; k += TPB) {
        const int p   = k >> 3;
        const int slt = k & 7;
        const int wpo = (slt - p) & 7;       // un-swizzle
        if (wpo < 7) {
            const unsigned int v = ot[k];
            float2 o;
            o.x = __uint_as_float((v & 0xffffu) << 16);
            o.y = __uint_as_float(v & 0xffff0000u);
            *(float2*)&ob[(size_t)p * T_TOT + 2 * wpo] = o;   // 8B aligned
        }
    }
}

extern "C" void kernel_launch(void* const* d_in, const int* in_sizes, int n_in,
                              void* d_out, int out_size, void* d_ws, size_t ws_size,
                              hipStream_t stream) {
    (void)in_sizes; (void)n_in; (void)out_size; (void)d_ws; (void)ws_size;
    const float* x = (const float*)d_in[0];
    float* out     = (float*)d_out;
    const int nblocks = 8 * 32 * NCH;        // 7424
    hipLaunchKernelGGL(tscorr_kernel, dim3(nblocks), dim3(TPB), 0, stream, x, out);
}

// Round 11
// 75.763 us; speedup vs baseline: 1.4295x; 1.4295x over previous
//
#include <hip/hip_runtime.h>

typedef _Float16 half2_t __attribute__((ext_vector_type(2)));

#define TPB    256
#define NF     32
#define T_TOT  406
#define LLEN   2048
#define NPAIR  496
#define NCH    29          // chunks per batch; 29*14 = 406 exactly
#define WPB    14          // windows per chunk (7 window-pairs)
#define W2S    36          // W2 row stride (u32): 16B-aligned rows, bank-rotating
#define STSTR  15          // st row stride (float2)
#define OTS    8           // ot row stride (u32 slots, 7 used, swizzled)

#if __has_builtin(__builtin_amdgcn_fdot2)
__device__ __forceinline__ float dot2(unsigned int a, unsigned int b, float c) {
    return __builtin_amdgcn_fdot2(__builtin_bit_cast(half2_t, a),
                                  __builtin_bit_cast(half2_t, b), c, false);
}
#else
__device__ __forceinline__ float dot2(unsigned int a, unsigned int b, float c) {
    const half2_t ha = __builtin_bit_cast(half2_t, a);
    const half2_t hb = __builtin_bit_cast(half2_t, b);
    return c + (float)ha.x * (float)hb.x + (float)ha.y * (float)hb.y;
}
#endif

__device__ __forceinline__ unsigned int packh2(float a, float b) {
    half2_t h;
    h.x = (_Float16)a;
    h.y = (_Float16)b;
    return __builtin_bit_cast(unsigned int, h);
}

__device__ __forceinline__ unsigned int f2bf(float f) {
    unsigned int u = __float_as_uint(f);
    u += 0x7fffu + ((u >> 16) & 1u);           // RNE
    return u >> 16;
}

__global__ __launch_bounds__(TPB)
void tscorr_kernel(const float* __restrict__ x, float* __restrict__ out) {
    // W2[parity][m][f]: f16-pair-packed u32. parity 0: rows (2m,2m+1);
    // parity 1: rows (2m+1,2m+2). Row stride 36 u32 = 144B (16B-aligned).
    __shared__ alignas(16) unsigned int W2[2][44][W2S];   // 12672 B
    __shared__ float2       st[NF * STSTR];               //  3840 B
    __shared__ unsigned int ot[NPAIR * OTS];              // 15872 B

    const int tid = threadIdx.x;

    // XCD-pinned decode: all 29 chunks of batch b run on XCD b%8
    const int n     = blockIdx.x;
    const int xcd   = n & 7;
    const int slot  = n >> 3;            // 0..927
    const int bidx  = slot / NCH;        // 0..31
    const int chunk = slot - bidx * NCH; // 0..28
    const int b     = xcd + 8 * bidx;

    const int l0     = chunk * (WPB * 5);    // chunk*70
    const int lstart = l0 & ~3;              // 16B-aligned
    const int off    = l0 - lstart;          // 0 or 2 (even)
    const float* xb  = x + (size_t)b * NF * LLEN;

    // ------------- stage: float4 loads -> f16 pairs, both parities -------------
    {
        const int f  = tid >> 3;             // 0..31
        const int p4 = tid & 7;              // 0..7
        #pragma unroll
        for (int it = 0; it < 3; ++it) {
            const int grp = p4 + it * 8;     // 0..23
            if (grp < 22) {                  // rows 0..87 (+ guarded row 88)
                const int pos = grp * 4;
                const float4 v = *(const float4*)&xb[f * LLEN + lstart + pos];
                const float v4 = (lstart + pos + 4 < LLEN)
                                     ? xb[f * LLEN + lstart + pos + 4] : 0.f;
                W2[0][2 * grp    ][f] = packh2(v.x, v.y);
                W2[0][2 * grp + 1][f] = packh2(v.z, v.w);
                W2[1][2 * grp    ][f] = packh2(v.y, v.z);
                W2[1][2 * grp + 1][f] = packh2(v.w, v4);   // row 88 never consumed
            }
        }
    }
    __syncthreads();

    // ------------- cooperative stats via dot2: (f, tloc) columns -------------
    {
        const unsigned int ONES = packh2(1.f, 1.f);   // const-folds to 0x3C003C00
        for (int idx = tid; idx < NF * WPB; idx += TPB) {
            const int tloc = idx >> 5;       // 0..13
            const int ff   = idx & 31;       // lanes span banks
            const int par  = tloc & 1;
            const int ms   = (off + 5 * tloc - par) >> 1;
            const unsigned int* p0 = &W2[par][ms][ff];
            float S = 0.f, G = 0.f;
            #pragma unroll
            for (int q = 0; q < 10; ++q) {
                const unsigned int h = p0[q * W2S];
                S = dot2(h, ONES, S);        // sum x
                G = dot2(h, h, G);           // sum x^2
            }
            const float pp = S * 0.2236067977f;         // sqrt(20)*mu
            const float nn = sqrtf(fmaxf(G - pp * pp, 0.f));
            st[ff * STSTR + tloc] = make_float2(pp, nn);
        }
    }

    // -------- main: thread = (pair-block pb, window-pair wp), dot2 Gram --------
    const bool active = (tid < 252);
    const int  wp = tid / 36;                // 0..6
    const int  pb = tid - wp * 36;           // 0..35
    int bi = 0, r2 = active ? pb : 0;
    while (r2 >= 8 - bi) { r2 -= 8 - bi; ++bi; }
    const int bj = bi + r2;

    float A0[4][4], A1[4][4];
    if (active) {
        #pragma unroll
        for (int r = 0; r < 4; ++r)
            #pragma unroll
            for (int c = 0; c < 4; ++c) { A0[r][c] = 0.f; A1[r][c] = 0.f; }

        const int m0 = (off >> 1) + 5 * wp;  // even window start pair

        // window 0 (even parity)
        {
            const unsigned int* pi = &W2[0][m0][4 * bi];
            const unsigned int* pj = &W2[0][m0][4 * bj];
            #pragma unroll
            for (int q = 0; q < 10; ++q) {
                const uint4 vi = *(const uint4*)&pi[q * W2S];
                const uint4 vj = *(const uint4*)&pj[q * W2S];
                const unsigned int ia[4] = {vi.x, vi.y, vi.z, vi.w};
                const unsigned int jb[4] = {vj.x, vj.y, vj.z, vj.w};
                #pragma unroll
                for (int r = 0; r < 4; ++r)
                    #pragma unroll
                    for (int c = 0; c < 4; ++c)
                        A0[r][c] = dot2(ia[r], jb[c], A0[r][c]);
            }
        }
        // window 1 (odd parity), starts 5 rows later
        {
            const unsigned int* pi = &W2[1][m0 + 2][4 * bi];
            const unsigned int* pj = &W2[1][m0 + 2][4 * bj];
            #pragma unroll
            for (int q = 0; q < 10; ++q) {
                const uint4 vi = *(const uint4*)&pi[q * W2S];
                const uint4 vj = *(const uint4*)&pj[q * W2S];
                const unsigned int ia[4] = {vi.x, vi.y, vi.z, vi.w};
                const unsigned int jb[4] = {vj.x, vj.y, vj.z, vj.w};
                #pragma unroll
                for (int r = 0; r < 4; ++r)
                    #pragma unroll
                    for (int c = 0; c < 4; ++c)
                        A1[r][c] = dot2(ia[r], jb[c], A1[r][c]);
            }
        }
    }
    __syncthreads();                          // st visible

    // ---------------- epilogue: normalize both windows, pack 2xbf16 ----------------
    if (active) {
        const int t0 = 2 * wp;                // local even window
        float2 sj0[4], sj1[4];
        #pragma unroll
        for (int c = 0; c < 4; ++c) {
            sj0[c] = st[(bj * 4 + c) * STSTR + t0];
            sj1[c] = st[(bj * 4 + c) * STSTR + t0 + 1];
        }
        #pragma unroll
        for (int r = 0; r < 4; ++r) {
            const int fi = bi * 4 + r;
            const float2 si0 = st[fi * STSTR + t0];
            const float2 si1 = st[fi * STSTR + t0 + 1];
            #pragma unroll
            for (int c = 0; c < 4; ++c) {
                const int fj = bj * 4 + c;
                if (fj > fi) {
                    const int p = fi * (63 - fi) / 2 + (fj - fi - 1);
                    const float num0 = A0[r][c] - si0.x * sj0[c].x;
                    const float den0 = si0.y * sj0[c].y + 1e-8f;
                    const float num1 = A1[r][c] - si1.x * sj1[c].x;
                    const float den1 = si1.y * sj1[c].y + 1e-8f;
                    const float v0 = num0 * __builtin_amdgcn_rcpf(den0);
                    const float v1 = num1 * __builtin_amdgcn_rcpf(den1);
                    ot[p * OTS + ((wp + p) & 7)] = f2bf(v0) | (f2bf(v1) << 16);
                }
            }
        }
    }
    __syncthreads();

    // ------------- sweep: ot -> out[b][p][chunk*14 + 2wp + {0,1}], float2 ----------
    float* ob = out + (size_t)b * NPAIR * T_TOT + chunk * WPB;
    for (int k = tid; k < NPAIR * OTS; k += TPB) {
        const int p   = k >> 3;
        const int slt = k & 7;
        const int wpo = (slt - p) & 7;       // un-swizzle
        if (wpo < 7) {
            const unsigned int v = ot[k];
            float2 o;
            o.x = __uint_as_float((v & 0xffffu) << 16);
            o.y = __uint_as_float(v & 0xffff0000u);
            *(float2*)&ob[(size_t)p * T_TOT + 2 * wpo] = o;   // 8B aligned
        }
    }
}

extern "C" void kernel_launch(void* const* d_in, const int* in_sizes, int n_in,
                              void* d_out, int out_size, void* d_ws, size_t ws_size,
                              hipStream_t stream) {
    (void)in_sizes; (void)n_in; (void)out_size; (void)d_ws; (void)ws_size;
    const float* x = (const float*)d_in[0];
    float* out     = (float*)d_out;
    const int nblocks = 8 * 32 * NCH;        // 7424
    hipLaunchKernelGGL(tscorr_kernel, dim3(nblocks), dim3(TPB), 0, stream, x, out);
}

// Round 12
// 61.684 us; speedup vs baseline: 1.7558x; 1.2283x over previous
//
#include <hip/hip_runtime.h>

typedef _Float16 half2_t __attribute__((ext_vector_type(2)));
typedef _Float16 f16x8   __attribute__((ext_vector_type(8)));
typedef float    f32x16  __attribute__((ext_vector_type(16)));

#define TPB    256
#define NF     32
#define T_TOT  406
#define LLEN   2048
#define NPAIR  496
#define NCH    29          // chunks per batch; 29*14 = 406 exactly
#define WPB    14          // windows per chunk (7 window-pairs)
#define W2S    36          // W2 row stride (u32)
#define ZS     32          // Z row stride (u32): lanes span banks, halves 2-way-free
#define OTS    8           // ot row stride (u32 slots, 7 used, swizzled)

__device__ __forceinline__ float dot2(unsigned int a, unsigned int b, float c) {
    return __builtin_amdgcn_fdot2(__builtin_bit_cast(half2_t, a),
                                  __builtin_bit_cast(half2_t, b), c, false);
}
__device__ __forceinline__ unsigned int pkrtz(float a, float b) {
    return __builtin_bit_cast(unsigned int, __builtin_amdgcn_cvt_pkrtz(a, b));
}

__global__ __launch_bounds__(TPB)
void tscorr_kernel(const float* __restrict__ x, float* __restrict__ out) {
    __shared__ union {
        unsigned int W2[2][44][W2S];     // 12672 B: f16-pair-packed X (2 parities)
        unsigned int ot[NPAIR * OTS];    // 15872 B: f16-pair out tile (epilogue+)
    } R;
    __shared__ unsigned int Zs[WPB * 10 * ZS];   // 17920 B: normalized z windows

    const int tid = threadIdx.x;

    // XCD-pinned decode: all 29 chunks of batch b run on XCD b%8
    const int n     = blockIdx.x;
    const int xcd   = n & 7;
    const int slot  = n >> 3;            // 0..927
    const int bidx  = slot / NCH;        // 0..31
    const int chunk = slot - bidx * NCH; // 0..28
    const int b     = xcd + 8 * bidx;

    const int l0     = chunk * (WPB * 5);    // chunk*70 (even)
    const int lstart = l0 & ~3;              // 16B-aligned
    const int off    = l0 - lstart;          // 0 or 2 (even)
    const float* xb  = x + (size_t)b * NF * LLEN;

    // ---------------- stage: float4 loads -> f16 pairs, both parities ----------------
    {
        const int f  = tid >> 3;             // 0..31
        const int p4 = tid & 7;              // 0..7
        #pragma unroll
        for (int it = 0; it < 3; ++it) {
            const int grp = p4 + it * 8;     // 0..23
            if (grp < 22) {                  // rows 0..87
                const int pos = grp * 4;
                const float4 v = *(const float4*)&xb[f * LLEN + lstart + pos];
                const float v4 = (lstart + pos + 4 < LLEN)
                                     ? xb[f * LLEN + lstart + pos + 4] : 0.f;
                R.W2[0][2 * grp    ][f] = pkrtz(v.x, v.y);
                R.W2[0][2 * grp + 1][f] = pkrtz(v.z, v.w);
                R.W2[1][2 * grp    ][f] = pkrtz(v.y, v.z);
                R.W2[1][2 * grp + 1][f] = pkrtz(v.w, v4);
            }
        }
    }
    __syncthreads();

    // ------- fused stats + Z-normalize: thread = (f, t) column, regs reused -------
    {
        const unsigned int ONES = 0x3C003C00u;        // (1.0h, 1.0h)
        for (int idx = tid; idx < NF * WPB; idx += TPB) {   // 448 columns
            const int t   = idx >> 5;        // 0..13
            const int ff  = idx & 31;        // lanes span all banks
            const int par = t & 1;
            const int ms  = (off + 5 * t - par) >> 1;
            const unsigned int* p0 = &R.W2[par][ms][ff];
            unsigned int h[10];
            float S = 0.f, G = 0.f;
            #pragma unroll
            for (int q = 0; q < 10; ++q) {
                h[q] = p0[q * W2S];
                S = dot2(h[q], ONES, S);     // sum x
                G = dot2(h[q], h[q], G);     // sum x^2
            }
            const float nn = sqrtf(fmaxf(G - S * S * 0.05f, 0.f));
            const float rn = __builtin_amdgcn_rcpf(fmaxf(nn, 1e-6f));
            const float mb = -(S * 0.05f) * rn;       // -mu*rn
            unsigned int* zo = &Zs[(t * 10) * ZS + ff];
            #pragma unroll
            for (int q = 0; q < 10; ++q) {
                const half2_t hp = __builtin_bit_cast(half2_t, h[q]);
                const float z0 = fmaf((float)hp.x, rn, mb);
                const float z1 = fmaf((float)hp.y, rn, mb);
                zo[q * ZS] = pkrtz(z0, z1);
            }
        }
    }
    __syncthreads();

    // -------- main: wave = window-pair, MFMA Gram of normalized Z --------
    // A/B fragments identical (Gram): lane l: row/col = l&31, k = 8*(l>>5)+e.
    // K=20 = one full K=16 mfma + one mfma with only k=16..19 live (rest zeroed).
    {
        const int wv   = tid >> 6;
        const int lane = tid & 63;
        const int j    = lane & 31;          // C column
        const int hi   = lane >> 5;

        for (int pr = wv; pr < 7; pr += 4) { // waves 0-2: 2 pairs, wave 3: 1
            f32x16 C0, C1;
            #pragma unroll
            for (int r = 0; r < 16; ++r) { C0[r] = 0.f; C1[r] = 0.f; }

            #pragma unroll
            for (int w = 0; w < 2; ++w) {
                const int t = 2 * pr + w;
                const unsigned int* base = &Zs[(t * 10 + 4 * hi) * ZS + j];
                union { unsigned int u[4]; f16x8 h; } u1;
                u1.u[0] = base[0];
                u1.u[1] = base[ZS];
                u1.u[2] = base[2 * ZS];
                u1.u[3] = base[3 * ZS];
                union { unsigned int u[4]; f16x8 h; } u2;
                u2.u[2] = 0u; u2.u[3] = 0u;
                if (hi == 0) {               // k=16..19 live only in low half
                    const unsigned int* b2 = &Zs[(t * 10 + 8) * ZS + j];
                    u2.u[0] = b2[0];
                    u2.u[1] = b2[ZS];
                } else { u2.u[0] = 0u; u2.u[1] = 0u; }
                if (w == 0) {
                    C0 = __builtin_amdgcn_mfma_f32_32x32x16_f16(u1.h, u1.h, C0, 0, 0, 0);
                    C0 = __builtin_amdgcn_mfma_f32_32x32x16_f16(u2.h, u2.h, C0, 0, 0, 0);
                } else {
                    C1 = __builtin_amdgcn_mfma_f32_32x32x16_f16(u1.h, u1.h, C1, 0, 0, 0);
                    C1 = __builtin_amdgcn_mfma_f32_32x32x16_f16(u2.h, u2.h, C1, 0, 0, 0);
                }
            }

            // epilogue: C IS the correlation; pack f16 pair, upper-tri only
            #pragma unroll
            for (int r = 0; r < 16; ++r) {
                const int il = (r & 3) + 8 * (r >> 2);     // compile-time
                const int i  = il + 4 * hi;                // C row
                if (j > i) {
                    const int p = i * (63 - i) / 2 + (j - i - 1);
                    R.ot[p * OTS + ((pr + p) & 7)] = pkrtz(C0[r], C1[r]);
                }
            }
        }
    }
    __syncthreads();

    // ------------- sweep: ot (f16 pairs) -> out[b][p][chunk*14 + 2wp + {0,1}] ------
    float* ob = out + (size_t)b * NPAIR * T_TOT + chunk * WPB;
    for (int k = tid; k < NPAIR * OTS; k += TPB) {
        const int p   = k >> 3;
        const int slt = k & 7;
        const int wpo = (slt - p) & 7;       // un-swizzle
        if (wpo < 7) {
            const half2_t h = __builtin_bit_cast(half2_t, R.ot[k]);
            float2 o;
            o.x = (float)h.x;
            o.y = (float)h.y;
            *(float2*)&ob[(size_t)p * T_TOT + 2 * wpo] = o;   // 8B aligned
        }
    }
}

extern "C" void kernel_launch(void* const* d_in, const int* in_sizes, int n_in,
                              void* d_out, int out_size, void* d_ws, size_t ws_size,
                              hipStream_t stream) {
    (void)in_sizes; (void)n_in; (void)out_size; (void)d_ws; (void)ws_size;
    const float* x = (const float*)d_in[0];
    float* out     = (float*)d_out;
    const int nblocks = 8 * 32 * NCH;        // 7424
    hipLaunchKernelGGL(tscorr_kernel, dim3(nblocks), dim3(TPB), 0, stream, x, out);
}